// Round 1
// baseline (1448.351 us; speedup 1.0000x reference)
//
#include <hip/hip_runtime.h>
#include <cstdint>
#include <cstddef>

#define B_SZ 8
#define T_LEN 4096
#define HD 1024
#define MTOT (B_SZ * T_LEN)   // 32768 tokens

typedef unsigned short u16;
typedef __attribute__((ext_vector_type(8))) short bf16x8;
typedef __attribute__((ext_vector_type(4))) float f32x4;

static __device__ __forceinline__ float bf2f(u16 u) {
    union { unsigned i; float f; } v; v.i = ((unsigned)u) << 16; return v.f;
}
static __device__ __forceinline__ u16 f2bf(float f) {
    union { float f; unsigned i; } v; v.f = f;
    unsigned r = v.i + 0x7fffu + ((v.i >> 16) & 1u);
    return (u16)(r >> 16);
}
static __device__ __forceinline__ float sigm(float x) { return 1.f / (1.f + __expf(-x)); }
static __device__ __forceinline__ float tanh_fast(float x) { return 1.f - 2.f / (1.f + __expf(2.f * x)); }

static __device__ __forceinline__ void gload_lds16(const void* g, void* l) {
    __builtin_amdgcn_global_load_lds((const __attribute__((address_space(1))) void*)g,
                                     (__attribute__((address_space(3))) void*)l, 16, 0, 0);
}

// ---- K0: weights f32 -> bf16, concatenated [v(1024); g(1024); t(1024); r(1024); u-row + pad(128)]
__global__ __launch_bounds__(256) void prep_weights(
    const float* __restrict__ Wp, const float* __restrict__ Wg,
    const float* __restrict__ Wt, const float* __restrict__ Wr,
    const float* __restrict__ Wo, u16* __restrict__ wcat, u16* __restrict__ wob)
{
    int i = blockIdx.x * 256 + threadIdx.x;   // float4 index
    const int T1 = 4224 * 256;                // wcat in float4 units (1024/4 per row)
    const int T2 = 1024 * 256;                // wob
    if (i < T1) {
        int r = i >> 8, kq = i & 255;
        float4 v;
        if      (r < 1024)  v = ((const float4*)Wp)[(size_t)(r + 1) * 256 + kq];   // v-rows: Wp[1..1024]
        else if (r < 2048)  v = ((const float4*)Wg)[(size_t)(r - 1024) * 256 + kq];
        else if (r < 3072)  v = ((const float4*)Wt)[(size_t)(r - 2048) * 256 + kq];
        else if (r < 4096)  v = ((const float4*)Wr)[(size_t)(r - 3072) * 256 + kq];
        else if (r == 4096) v = ((const float4*)Wp)[kq];                           // u-row: Wp[0]
        else { v.x = 0.f; v.y = 0.f; v.z = 0.f; v.w = 0.f; }                       // pad
        ushort4 o; o.x = f2bf(v.x); o.y = f2bf(v.y); o.z = f2bf(v.z); o.w = f2bf(v.w);
        ((ushort4*)wcat)[i] = o;
    } else if (i < T1 + T2) {
        int j = i - T1;
        float4 v = ((const float4*)Wo)[j];
        ushort4 o; o.x = f2bf(v.x); o.y = f2bf(v.y); o.z = f2bf(v.z); o.w = f2bf(v.w);
        ((ushort4*)wob)[j] = o;
    }
}

// ---- K1: LayerNorm, one block per token row ---------------------------------
__global__ __launch_bounds__(256) void ln_kernel(
    const float* __restrict__ x, const float* __restrict__ gamma,
    const float* __restrict__ beta, u16* __restrict__ xnb)
{
    __shared__ float red[8];
    const int row = blockIdx.x, tid = threadIdx.x;
    const float4 v = ((const float4*)(x + (size_t)row * HD))[tid];
    float s  = v.x + v.y + v.z + v.w;
    float sq = v.x * v.x + v.y * v.y + v.z * v.z + v.w * v.w;
    #pragma unroll
    for (int off = 32; off > 0; off >>= 1) {
        s  += __shfl_down(s, off);
        sq += __shfl_down(sq, off);
    }
    if ((tid & 63) == 0) { red[tid >> 6] = s; red[4 + (tid >> 6)] = sq; }
    __syncthreads();
    const float S   = red[0] + red[1] + red[2] + red[3];
    const float SQ  = red[4] + red[5] + red[6] + red[7];
    const float mu  = S * (1.f / HD);
    const float var = SQ * (1.f / HD) - mu * mu;
    const float rs  = rsqrtf(var + 1e-5f);
    const float4 gg = ((const float4*)gamma)[tid];
    const float4 bb = ((const float4*)beta)[tid];
    ushort4 o;
    o.x = f2bf((v.x - mu) * rs * gg.x + bb.x);
    o.y = f2bf((v.y - mu) * rs * gg.y + bb.y);
    o.z = f2bf((v.z - mu) * rs * gg.z + bb.z);
    o.w = f2bf((v.w - mu) * rs * gg.w + bb.w);
    ((ushort4*)(xnb + (size_t)row * HD))[tid] = o;
}

// ---- K2/K4: bf16 MFMA GEMM, C = A[M][1024] x W[N][1024]^T, 128x128 tile -----
// mode 0: projection epilogue (V,G,T,R bf16 + u f32); mode 1: plain f32 store
__global__ __launch_bounds__(256) void gemm_bt(
    const u16* __restrict__ A, const u16* __restrict__ W, int mode,
    const float* __restrict__ bp,
    u16* __restrict__ Vb, u16* __restrict__ Gb, u16* __restrict__ Tb, u16* __restrict__ Rb,
    float* __restrict__ ub, float* __restrict__ Cout)
{
    __shared__ u16 sA[128 * 32];
    __shared__ u16 sB[128 * 32];
    const int mtile = blockIdx.x, ntile = blockIdx.y;
    const int tid = threadIdx.x;
    const int lane = tid & 63, wave = tid >> 6;
    const u16* Ab = A + (size_t)mtile * 128 * 1024;
    const u16* Wb = W + (size_t)ntile * 128 * 1024;

    const int r0 = tid >> 2;            // rows 0..63
    const int r1 = r0 + 64;             // rows 64..127
    const int kq = (tid & 3) * 8;       // 8-elem (16B) chunk within 32-wide k-slab

    f32x4 acc[4][4] = {};
    const int wm = (wave >> 1) * 64, wn = (wave & 1) * 64;

    for (int k0 = 0; k0 < 1024; k0 += 32) {
        gload_lds16(Ab + (size_t)r0 * 1024 + k0 + kq, sA + (size_t)tid * 8);
        gload_lds16(Ab + (size_t)r1 * 1024 + k0 + kq, sA + (size_t)(tid + 256) * 8);
        gload_lds16(Wb + (size_t)r0 * 1024 + k0 + kq, sB + (size_t)tid * 8);
        gload_lds16(Wb + (size_t)r1 * 1024 + k0 + kq, sB + (size_t)(tid + 256) * 8);
        __syncthreads();
        bf16x8 af[4], bfr[4];
        #pragma unroll
        for (int i = 0; i < 4; ++i)
            af[i]  = *(const bf16x8*)(sA + (wm + i * 16 + (lane & 15)) * 32 + (lane >> 4) * 8);
        #pragma unroll
        for (int i = 0; i < 4; ++i)
            bfr[i] = *(const bf16x8*)(sB + (wn + i * 16 + (lane & 15)) * 32 + (lane >> 4) * 8);
        #pragma unroll
        for (int mi = 0; mi < 4; ++mi)
            #pragma unroll
            for (int ni = 0; ni < 4; ++ni)
                acc[mi][ni] = __builtin_amdgcn_mfma_f32_16x16x32_bf16(af[mi], bfr[ni], acc[mi][ni], 0, 0, 0);
        __syncthreads();
    }

    #pragma unroll
    for (int mi = 0; mi < 4; ++mi) {
        #pragma unroll
        for (int ni = 0; ni < 4; ++ni) {
            const int n = ntile * 128 + wn + ni * 16 + (lane & 15);
            #pragma unroll
            for (int j = 0; j < 4; ++j) {
                const int m = mtile * 128 + wm + mi * 16 + (lane >> 4) * 4 + j;
                float val = acc[mi][ni][j];
                if (mode == 1) {
                    Cout[(size_t)m * 1024 + n] = val;
                } else if (ntile < 8) {
                    Vb[(size_t)m * 1024 + n] = f2bf(val + bp[1 + n]);
                } else if (ntile < 16) {
                    Gb[(size_t)m * 1024 + (n - 1024)] = f2bf(sigm(val));
                } else if (ntile < 24) {
                    Tb[(size_t)m * 1024 + (n - 2048)] = f2bf(tanh_fast(val));
                } else if (ntile < 32) {
                    Rb[(size_t)m * 1024 + (n - 3072)] = f2bf(sigm(val));
                } else {
                    if (n == 4096) ub[m] = val + bp[0];   // u column, no pad stores
                }
            }
        }
    }
}

// ---- K3: strictly-sequential dual cumsum (f32 active, fp16 ghost) -----------
__global__ __launch_bounds__(256) void scan_seq(
    const u16* __restrict__ Vb, const u16* __restrict__ Gb,
    const u16* __restrict__ Tb, const u16* __restrict__ Rb,
    const float* __restrict__ ub, u16* __restrict__ outb,
    float* __restrict__ act_last, float* __restrict__ gho_last)
{
    const int b = blockIdx.x >> 2;
    const int d = ((blockIdx.x & 3) << 8) + threadIdx.x;
    const size_t base = (size_t)b * T_LEN * HD + d;
    const float* u_b = ub + (size_t)b * T_LEN;
    float acc_a = 0.f;
    _Float16 acc_g = (_Float16)0.f;
    #pragma unroll 8
    for (int t = 0; t < T_LEN; ++t) {
        const size_t idx = base + (size_t)t * HD;
        const float v  = bf2f(Vb[idx]);
        const float g  = bf2f(Gb[idx]);
        const float th = bf2f(Tb[idx]);
        const float r  = bf2f(Rb[idx]);
        const float u  = u_b[t];
        acc_a += u * v;                          // f32 sequential cumsum
        acc_g = acc_g + (_Float16)(g * th);      // fp16 RNE sequential cumsum (matches np)
        const float comb = acc_a + (float)acc_g;
        outb[idx] = f2bf(r * comb);
    }
    act_last[(size_t)b * HD + d] = acc_a;
    gho_last[(size_t)b * HD + d] = (float)acc_g;
}

extern "C" void kernel_launch(void* const* d_in, const int* in_sizes, int n_in,
                              void* d_out, int out_size, void* d_ws, size_t ws_size,
                              hipStream_t stream)
{
    const float* x   = (const float*)d_in[0];
    const float* gam = (const float*)d_in[1];
    const float* bet = (const float*)d_in[2];
    const float* Wp  = (const float*)d_in[3];
    const float* bp  = (const float*)d_in[4];
    const float* Wg  = (const float*)d_in[5];
    const float* Wt  = (const float*)d_in[6];
    const float* Wr  = (const float*)d_in[7];
    const float* Wo  = (const float*)d_in[8];

    float* out0     = (float*)d_out;                       // (B,T,H) f32
    float* act_last = out0 + (size_t)MTOT * HD;            // (B,1,D) f32
    float* gho_last = act_last + (size_t)B_SZ * HD;        // (B,1,D) fp16 values as f32

    char* ws = (char*)d_ws;
    const size_t SZ = (size_t)MTOT * HD * 2;               // 64 MiB (bf16 M x 1024)
    u16* xnb  = (u16*)(ws);                                // xn bf16; reused later as outb
    u16* Vb   = (u16*)(ws + SZ);
    u16* Gb   = (u16*)(ws + 2 * SZ);
    u16* Tb   = (u16*)(ws + 3 * SZ);
    u16* Rb   = (u16*)(ws + 4 * SZ);
    u16* wcat = (u16*)(ws + 5 * SZ);                       // 4224*1024*2 = 8,650,752 B
    u16* wob  = (u16*)(ws + 5 * SZ + 8650752);             // 1024*1024*2 = 2,097,152 B
    float* ub = (float*)(ws + 5 * SZ + 8650752 + 2097152); // 32768*4 B

    prep_weights<<<5248, 256, 0, stream>>>(Wp, Wg, Wt, Wr, Wo, wcat, wob);
    ln_kernel<<<MTOT, 256, 0, stream>>>(x, gam, bet, xnb);
    gemm_bt<<<dim3(256, 33), 256, 0, stream>>>(xnb, wcat, 0, bp, Vb, Gb, Tb, Rb, ub, nullptr);
    scan_seq<<<32, 256, 0, stream>>>(Vb, Gb, Tb, Rb, ub, xnb /*outb alias*/, act_last, gho_last);
    gemm_bt<<<dim3(256, 8), 256, 0, stream>>>(xnb, wob, 1, bp, nullptr, nullptr, nullptr, nullptr, nullptr, out0);
}

// Round 2
// 1103.977 us; speedup vs baseline: 1.3119x; 1.3119x over previous
//
#include <hip/hip_runtime.h>
#include <cstdint>
#include <cstddef>

#define B_SZ 8
#define T_LEN 4096
#define HD 1024
#define MTOT (B_SZ * T_LEN)   // 32768 tokens

typedef unsigned short u16;
typedef __attribute__((ext_vector_type(8))) short bf16x8;
typedef __attribute__((ext_vector_type(4))) float f32x4;

static __device__ __forceinline__ float bf2f(u16 u) {
    union { unsigned i; float f; } v; v.i = ((unsigned)u) << 16; return v.f;
}
static __device__ __forceinline__ u16 f2bf(float f) {
    union { float f; unsigned i; } v; v.f = f;
    unsigned r = v.i + 0x7fffu + ((v.i >> 16) & 1u);
    return (u16)(r >> 16);
}
static __device__ __forceinline__ float sigm(float x) { return 1.f / (1.f + __expf(-x)); }
static __device__ __forceinline__ float tanh_fast(float x) { return 1.f - 2.f / (1.f + __expf(2.f * x)); }

static __device__ __forceinline__ void gload_lds16(const void* g, void* l) {
    __builtin_amdgcn_global_load_lds((const __attribute__((address_space(1))) void*)g,
                                     (__attribute__((address_space(3))) void*)l, 16, 0, 0);
}

// ---- K0: weights f32 -> bf16: wcat = [v(1024); g(1024); t(1024); r(1024)], wob = Wo
__global__ __launch_bounds__(256) void prep_weights(
    const float* __restrict__ Wp, const float* __restrict__ Wg,
    const float* __restrict__ Wt, const float* __restrict__ Wr,
    const float* __restrict__ Wo, u16* __restrict__ wcat, u16* __restrict__ wob)
{
    int i = blockIdx.x * 256 + threadIdx.x;   // float4 index
    const int T1 = 4096 * 256;
    const int T2 = 1024 * 256;
    if (i < T1) {
        int r = i >> 8, kq = i & 255;
        float4 v;
        if      (r < 1024)  v = ((const float4*)Wp)[(size_t)(r + 1) * 256 + kq];   // v-rows: Wp[1..1024]
        else if (r < 2048)  v = ((const float4*)Wg)[(size_t)(r - 1024) * 256 + kq];
        else if (r < 3072)  v = ((const float4*)Wt)[(size_t)(r - 2048) * 256 + kq];
        else                v = ((const float4*)Wr)[(size_t)(r - 3072) * 256 + kq];
        ushort4 o; o.x = f2bf(v.x); o.y = f2bf(v.y); o.z = f2bf(v.z); o.w = f2bf(v.w);
        ((ushort4*)wcat)[i] = o;
    } else if (i < T1 + T2) {
        int j = i - T1;
        float4 v = ((const float4*)Wo)[j];
        ushort4 o; o.x = f2bf(v.x); o.y = f2bf(v.y); o.z = f2bf(v.z); o.w = f2bf(v.w);
        ((ushort4*)wob)[j] = o;
    }
}

// ---- K1: LayerNorm (f32) -> xn bf16, fused u[m] = xn_f32 . Wp[0] + bp[0] ----
__global__ __launch_bounds__(256) void ln_kernel(
    const float* __restrict__ x, const float* __restrict__ gamma,
    const float* __restrict__ beta, const float* __restrict__ Wp,
    const float* __restrict__ bp, u16* __restrict__ xnb, float* __restrict__ u)
{
    __shared__ float red[8];
    const int row = blockIdx.x, tid = threadIdx.x;
    const float4 v = ((const float4*)(x + (size_t)row * HD))[tid];
    float s  = v.x + v.y + v.z + v.w;
    float sq = v.x * v.x + v.y * v.y + v.z * v.z + v.w * v.w;
    #pragma unroll
    for (int off = 32; off > 0; off >>= 1) {
        s  += __shfl_down(s, off);
        sq += __shfl_down(sq, off);
    }
    if ((tid & 63) == 0) { red[tid >> 6] = s; red[4 + (tid >> 6)] = sq; }
    __syncthreads();
    const float S   = red[0] + red[1] + red[2] + red[3];
    const float SQ  = red[4] + red[5] + red[6] + red[7];
    const float mu  = S * (1.f / HD);
    const float var = SQ * (1.f / HD) - mu * mu;
    const float rs  = rsqrtf(var + 1e-5f);
    const float4 gg = ((const float4*)gamma)[tid];
    const float4 bb = ((const float4*)beta)[tid];
    const float x0 = (v.x - mu) * rs * gg.x + bb.x;
    const float x1 = (v.y - mu) * rs * gg.y + bb.y;
    const float x2 = (v.z - mu) * rs * gg.z + bb.z;
    const float x3 = (v.w - mu) * rs * gg.w + bb.w;
    ushort4 o; o.x = f2bf(x0); o.y = f2bf(x1); o.z = f2bf(x2); o.w = f2bf(x3);
    ((ushort4*)(xnb + (size_t)row * HD))[tid] = o;
    // fused u-dot against Wp row 0 (f32, matches reference precision closely)
    const float4 w0 = ((const float4*)Wp)[tid];
    float su = x0 * w0.x + x1 * w0.y + x2 * w0.z + x3 * w0.w;
    #pragma unroll
    for (int off = 32; off > 0; off >>= 1) su += __shfl_down(su, off);
    __syncthreads();                       // protect red[] reuse
    if ((tid & 63) == 0) red[tid >> 6] = su;
    __syncthreads();
    if (tid == 0) u[row] = red[0] + red[1] + red[2] + red[3] + bp[0];
}

// ---- K2/K4: bf16 MFMA GEMM, 128x128 tile, BK=64, conflict-free swizzled LDS -
// mode 0: projection epilogue (V,G,T,R bf16); mode 1: plain f32 store
__global__ __launch_bounds__(256) void gemm_bt(
    const u16* __restrict__ A, const u16* __restrict__ W, int mode,
    const float* __restrict__ bp,
    u16* __restrict__ Vb, u16* __restrict__ Gb, u16* __restrict__ Tb, u16* __restrict__ Rb,
    float* __restrict__ Cout)
{
    __shared__ u16 sA[128 * 64];
    __shared__ u16 sB[128 * 64];
    const int mtile = blockIdx.x, ntile = blockIdx.y;
    const int tid = threadIdx.x;
    const int lane = tid & 63, wave = tid >> 6;
    const u16* Ab = A + (size_t)mtile * 128 * 1024;
    const u16* Wb = W + (size_t)ntile * 128 * 1024;

    // staging map: linear LDS chunk q (16B) = row*8 + cl; stored chunk cl holds
    // global chunk cg = cl ^ (row&7)  (inverse-swizzled source, linear dest)
    int offj[4];
    #pragma unroll
    for (int j = 0; j < 4; ++j) {
        const int q = j * 256 + tid;
        const int row = q >> 3;
        const int cg = (q & 7) ^ (row & 7);
        offj[j] = row * 1024 + cg * 8;
    }

    f32x4 acc[4][4] = {};
    const int wm = (wave >> 1) * 64, wn = (wave & 1) * 64;
    const int rA = lane & 15;           // row-within-16 for frags
    const int clbase = lane & 7;        // swizzle key (row&7 of frag rows)

    for (int k0 = 0; k0 < 1024; k0 += 64) {
        #pragma unroll
        for (int j = 0; j < 4; ++j) {
            gload_lds16(Ab + offj[j] + k0, sA + (size_t)(j * 256 + tid) * 8);
            gload_lds16(Wb + offj[j] + k0, sB + (size_t)(j * 256 + tid) * 8);
        }
        __syncthreads();
        #pragma unroll
        for (int h = 0; h < 2; ++h) {
            const int cl = ((h << 2) + (lane >> 4)) ^ clbase;
            bf16x8 af[4], bfr[4];
            #pragma unroll
            for (int i = 0; i < 4; ++i)
                af[i]  = *(const bf16x8*)(sA + (size_t)(wm + i * 16 + rA) * 64 + cl * 8);
            #pragma unroll
            for (int i = 0; i < 4; ++i)
                bfr[i] = *(const bf16x8*)(sB + (size_t)(wn + i * 16 + rA) * 64 + cl * 8);
            #pragma unroll
            for (int mi = 0; mi < 4; ++mi)
                #pragma unroll
                for (int ni = 0; ni < 4; ++ni)
                    acc[mi][ni] = __builtin_amdgcn_mfma_f32_16x16x32_bf16(af[mi], bfr[ni], acc[mi][ni], 0, 0, 0);
        }
        __syncthreads();
    }

    #pragma unroll
    for (int mi = 0; mi < 4; ++mi) {
        #pragma unroll
        for (int ni = 0; ni < 4; ++ni) {
            const int n = ntile * 128 + wn + ni * 16 + (lane & 15);
            #pragma unroll
            for (int j = 0; j < 4; ++j) {
                const int m = mtile * 128 + wm + mi * 16 + (lane >> 4) * 4 + j;
                float val = acc[mi][ni][j];
                if (mode == 1) {
                    Cout[(size_t)m * 1024 + n] = val;
                } else if (ntile < 8) {
                    Vb[(size_t)m * 1024 + n] = f2bf(val + bp[1 + n]);
                } else if (ntile < 16) {
                    Gb[(size_t)m * 1024 + (n - 1024)] = f2bf(sigm(val));
                } else if (ntile < 24) {
                    Tb[(size_t)m * 1024 + (n - 2048)] = f2bf(tanh_fast(val));
                } else {
                    Rb[(size_t)m * 1024 + (n - 3072)] = f2bf(sigm(val));
                }
            }
        }
    }
}

// ---- K3: LDS-staged sequential dual cumsum ----------------------------------
// block = 4 waves; all waves stage (global_load_lds, double-buffered), wave 0
// runs the strictly-sequential scan (f32 active + fp16 ghost) from LDS.
#define TB 64
__global__ __launch_bounds__(256) void scan_lds(
    const u16* __restrict__ Vb, const u16* __restrict__ Gb,
    const u16* __restrict__ Tb, const u16* __restrict__ Rb,
    const float* __restrict__ ub, u16* __restrict__ outb,
    float* __restrict__ act_last, float* __restrict__ gho_last)
{
    __shared__ u16 sS[2][4][TB * 64];   // [dbuf][stream V,G,T,R][t][d]  64 KiB
    __shared__ float sU[2][TB];
    const int tid = threadIdx.x, lane = tid & 63, wave = tid >> 6;
    const int b  = blockIdx.x >> 4;
    const int d0 = (blockIdx.x & 15) * 64;
    const int bm0 = b * T_LEN;

    #define STAGE(nb, t0) do {                                                   \
        _Pragma("unroll")                                                        \
        for (int j = 0; j < 2; ++j) {                                            \
            const int q  = j * 256 + tid;                                        \
            const int tr = q >> 3, cc = q & 7;                                   \
            const size_t gofs = (size_t)(bm0 + (t0) + tr) * HD + d0 + cc * 8;    \
            gload_lds16(Vb + gofs, &sS[nb][0][q * 8]);                           \
            gload_lds16(Gb + gofs, &sS[nb][1][q * 8]);                           \
            gload_lds16(Tb + gofs, &sS[nb][2][q * 8]);                           \
            gload_lds16(Rb + gofs, &sS[nb][3][q * 8]);                           \
        }                                                                        \
        if (tid < TB) sU[nb][tid] = ub[bm0 + (t0) + tid];                        \
    } while (0)

    STAGE(0, 0);
    __syncthreads();

    float acc_a = 0.f;
    _Float16 acc_g = (_Float16)0.f;
    int cur = 0;
    for (int c = 0; c < T_LEN / TB; ++c) {
        if (c < T_LEN / TB - 1) STAGE(cur ^ 1, (c + 1) * TB);
        if (wave == 0) {
            #pragma unroll 4
            for (int tt = 0; tt < TB; ++tt) {
                const float v  = bf2f(sS[cur][0][tt * 64 + lane]);
                const float g  = bf2f(sS[cur][1][tt * 64 + lane]);
                const float th = bf2f(sS[cur][2][tt * 64 + lane]);
                const float r  = bf2f(sS[cur][3][tt * 64 + lane]);
                const float uu = sU[cur][tt];
                acc_a = fmaf(uu, v, acc_a);                 // f32 sequential cumsum
                acc_g = acc_g + (_Float16)(g * th);         // fp16 RNE sequential cumsum
                const float comb = acc_a + (float)acc_g;
                outb[(size_t)(bm0 + c * TB + tt) * HD + d0 + lane] = f2bf(r * comb);
            }
        }
        __syncthreads();
        cur ^= 1;
    }
    if (wave == 0) {
        act_last[(size_t)b * HD + d0 + lane] = acc_a;
        gho_last[(size_t)b * HD + d0 + lane] = (float)acc_g;
    }
    #undef STAGE
}

extern "C" void kernel_launch(void* const* d_in, const int* in_sizes, int n_in,
                              void* d_out, int out_size, void* d_ws, size_t ws_size,
                              hipStream_t stream)
{
    const float* x   = (const float*)d_in[0];
    const float* gam = (const float*)d_in[1];
    const float* bet = (const float*)d_in[2];
    const float* Wp  = (const float*)d_in[3];
    const float* bp  = (const float*)d_in[4];
    const float* Wg  = (const float*)d_in[5];
    const float* Wt  = (const float*)d_in[6];
    const float* Wr  = (const float*)d_in[7];
    const float* Wo  = (const float*)d_in[8];

    float* out0     = (float*)d_out;                       // (B,T,H) f32
    float* act_last = out0 + (size_t)MTOT * HD;            // (B,D) f32
    float* gho_last = act_last + (size_t)B_SZ * HD;        // (B,D) fp16-valued f32

    char* ws = (char*)d_ws;
    const size_t SZ = (size_t)MTOT * HD * 2;               // 64 MiB per bf16 plane
    u16* xnb  = (u16*)(ws);                                // xn bf16; reused as out-of-scan
    u16* Vb   = (u16*)(ws + SZ);
    u16* Gb   = (u16*)(ws + 2 * SZ);
    u16* Tb   = (u16*)(ws + 3 * SZ);
    u16* Rb   = (u16*)(ws + 4 * SZ);
    u16* wcat = (u16*)(ws + 5 * SZ);                       // 4096*1024*2 = 8,388,608 B
    u16* wob  = (u16*)(ws + 5 * SZ + 8388608);             // 1024*1024*2 = 2,097,152 B
    float* ub = (float*)(ws + 5 * SZ + 8388608 + 2097152); // 32768*4 B

    prep_weights<<<5120, 256, 0, stream>>>(Wp, Wg, Wt, Wr, Wo, wcat, wob);
    ln_kernel<<<MTOT, 256, 0, stream>>>(x, gam, bet, Wp, bp, xnb, ub);
    gemm_bt<<<dim3(256, 32), 256, 0, stream>>>(xnb, wcat, 0, bp, Vb, Gb, Tb, Rb, nullptr);
    scan_lds<<<128, 256, 0, stream>>>(Vb, Gb, Tb, Rb, ub, xnb /*out staging*/, act_last, gho_last);
    gemm_bt<<<dim3(256, 8), 256, 0, stream>>>(xnb, wob, 1, bp, nullptr, nullptr, nullptr, nullptr, out0);
}